// Round 9
// baseline (1773.114 us; speedup 1.0000x reference)
//
#include <hip/hip_runtime.h>

// ---------------- workspace offsets (in floats) ----------------
static constexpr size_t O_H0    = 0;          // 16384*256 (also split-K partials later)
static constexpr size_t O_H1P   = 4194304;    // 16384*78
static constexpr size_t O_X     = 5473216;    // 16384*156
static constexpr size_t O_A1    = 8029120;    // 512*1024
static constexpr size_t O_A2    = 8553408;
static constexpr size_t O_A3    = 9077696;
static constexpr size_t O_H4    = 9601984;    // 16384*156
static constexpr size_t O_H6    = 12157888;   // 16384*156
static constexpr size_t O_H1W2  = 14713792;   // 16384*312
static constexpr size_t O_H2    = 19825600;   // 16384*312
static constexpr size_t O_H2W3  = 24937408;   // 16384*624
static constexpr size_t O_H3    = 35161024;   // 16384*624
static constexpr size_t O_HG    = 45384640;   // 512*1092
static constexpr size_t O_FCG1O = 45943744;   // 512*1024
static constexpr size_t O_M     = 46468032;   // 3*3*26*96
static constexpr size_t O_F     = 46535424;   // 512*288
static constexpr size_t O_V     = 46682880;   // 512*128
static constexpr size_t O_XC    = 46748416;   // 512*256
static constexpr size_t O_FC1O  = 46879488;   // 512*1024
static constexpr size_t O_FC2O  = 47403776;   // 512*512
static constexpr size_t O_PART  = 47665920;   // 2*64*256
static constexpr size_t O_MV    = 47698688;   // 1024
static constexpr size_t O_BT21  = 47699712;   // 96*96*3
static constexpr size_t O_BT31  = 47727360;
static constexpr size_t O_W32T  = 47755008;   // end 47782656 floats = 191.1 MB
// aliases (sequentially dead regions reused):
static constexpr size_t O_XW1  = O_H0;             // after decoder done
static constexpr size_t O_SK   = O_H0;             // split-K partials (head phase)
static constexpr size_t O_H1   = O_X;              // after XW1 GEMM
static constexpr size_t O_H4W2 = O_H1W2;           // after h2 agg
static constexpr size_t O_H5   = O_H2W3;           // after h3 agg
static constexpr size_t O_R10  = O_H1W2;           // protein phase (after hg)
static constexpr size_t O_R20  = O_H1W2 + 1687296;
static constexpr size_t O_R30  = O_H1W2 + 3374592;
static constexpr size_t O_N21  = O_H2W3;           // protein phase (after hg)
static constexpr size_t O_N31  = O_H2W3 + 5061888;

// ---------------- split-K 64x64 GEMM: writes partials, no bias/act ----------------
// float4 fast-path staging for interior tiles (all call sites: K%4==0, N%4==0).
__global__ __launch_bounds__(256) void gemm_sk(
    const float* __restrict__ A, const float* __restrict__ Bm,
    float* __restrict__ PT, int M, int N, int K, int KS)
{
  __shared__ __align__(16) float sA[16 * 68];
  __shared__ __align__(16) float sB[16 * 68];
  const int tid = threadIdx.x;
  const int m0 = blockIdx.y * 64, n0 = blockIdx.x * 64;
  const int kb = blockIdx.z * KS;
  const int ke = min(K, kb + KS);
  const int tx = tid & 15, ty = tid >> 4;
  const bool fullM = (m0 + 64 <= M), fullN = (n0 + 64 <= N);
  float acc[4][4] = {};
  for (int k0 = kb; k0 < ke; k0 += 16) {
    const bool fullK = (k0 + 16 <= ke);
    if (fullM && fullK) {
      const int am = tid >> 2, ak = (tid & 3) * 4;
      const float4 v = *(const float4*)&A[(size_t)(m0 + am) * K + k0 + ak];
      sA[(ak + 0) * 68 + am] = v.x; sA[(ak + 1) * 68 + am] = v.y;
      sA[(ak + 2) * 68 + am] = v.z; sA[(ak + 3) * 68 + am] = v.w;
    } else {
#pragma unroll
      for (int s2 = 0; s2 < 4; s2++) {
        int idx = tid + s2 * 256;
        int am = idx >> 4, ak = idx & 15;
        int gm = m0 + am, gk = k0 + ak;
        float va = 0.f;
        if (gm < M && gk < ke) va = A[(size_t)gm * K + gk];
        sA[ak * 68 + am] = va;
      }
    }
    if (fullN && fullK) {
      const int bk = tid >> 4, bn4 = (tid & 15) * 4;
      *(float4*)&sB[bk * 68 + bn4] = *(const float4*)&Bm[(size_t)(k0 + bk) * N + n0 + bn4];
    } else {
#pragma unroll
      for (int s2 = 0; s2 < 4; s2++) {
        int idx = tid + s2 * 256;
        int bk2 = idx >> 6, bn = idx & 63;
        int gk2 = k0 + bk2, gn = n0 + bn;
        float vb = 0.f;
        if (gk2 < ke && gn < N) vb = Bm[(size_t)gk2 * N + gn];
        sB[bk2 * 68 + bn] = vb;
      }
    }
    __syncthreads();
#pragma unroll
    for (int kk = 0; kk < 16; kk++) {
      const float4 a4 = *(const float4*)&sA[kk * 68 + ty * 4];
      const float4 b4 = *(const float4*)&sB[kk * 68 + tx * 4];
      const float ra[4] = {a4.x, a4.y, a4.z, a4.w};
      const float rb[4] = {b4.x, b4.y, b4.z, b4.w};
#pragma unroll
      for (int i2 = 0; i2 < 4; i2++)
#pragma unroll
        for (int j2 = 0; j2 < 4; j2++)
          acc[i2][j2] = fmaf(ra[i2], rb[j2], acc[i2][j2]);
    }
    __syncthreads();
  }
  float* P = PT + (size_t)blockIdx.z * M * N;
#pragma unroll
  for (int i2 = 0; i2 < 4; i2++) {
    int gm = m0 + ty * 4 + i2;
    if (gm >= M) continue;
#pragma unroll
    for (int j2 = 0; j2 < 4; j2++) {
      int gn = n0 + tx * 4 + j2;
      if (gn >= N) continue;
      P[(size_t)gm * N + gn] = acc[i2][j2];
    }
  }
}

// reduce split-K partials (deterministic slice order). nmask = N-1 (N power of two).
__global__ void skred_kernel(const float* __restrict__ PT, const float* __restrict__ bias,
                             float* __restrict__ C, int MN, int nmask, int S, int act)
{
  int i = blockIdx.x * 256 + threadIdx.x;
  if (i >= MN) return;
  float s = 0.f;
  for (int z = 0; z < S; z++) s += PT[(size_t)z * MN + i];
  if (bias) s += bias[i & nmask];
  if (act) s = fmaxf(s, 0.f);
  C[i] = s;
}

// ---------------- 128x64 tiled fp32 GEMM, 8x4 acc (tall-M cases) ----------------
template<int AMODE, int ACT>
__global__ __launch_bounds__(256) void gemm2_k(
    const float* __restrict__ A, const float* __restrict__ Bm,
    const float* __restrict__ bias, float* __restrict__ C,
    int M, int N, int K, const float* __restrict__ A2)
{
  __shared__ __align__(16) float sA[16 * 132];  // [k][m]
  __shared__ __align__(16) float sB[16 * 68];   // [k][n]
  const int tid = threadIdx.x;
  const int m0 = blockIdx.y * 128, n0 = blockIdx.x * 64;
  const int tx = tid & 15, ty = tid >> 4;
  float acc[8][4] = {};
  for (int k0 = 0; k0 < K; k0 += 16) {
#pragma unroll
    for (int s2 = 0; s2 < 2; s2++) {
      int idx = tid + s2 * 256;
      int am = idx >> 2, kq = idx & 3;
      int gm = m0 + am;
#pragma unroll
      for (int j = 0; j < 4; j++) {
        int gk = k0 + kq * 4 + j;
        float va = 0.f;
        if (gm < M && gk < K) {
          if (AMODE == 0) va = A[(size_t)gm * K + gk];
          else            va = (gk < 64) ? A[gm * 64 + gk] : A2[gm * 78 + gk - 64];
        }
        sA[(kq * 4 + j) * 132 + am] = va;
      }
    }
    {
      int bk = tid >> 4, bn4 = tid & 15;
      int gk2 = k0 + bk;
#pragma unroll
      for (int j = 0; j < 4; j++) {
        int gn = n0 + bn4 * 4 + j;
        float vb = 0.f;
        if (gk2 < K && gn < N) vb = Bm[(size_t)gk2 * N + gn];
        sB[bk * 68 + bn4 * 4 + j] = vb;
      }
    }
    __syncthreads();
#pragma unroll
    for (int kk = 0; kk < 16; kk++) {
      const float4 a0 = *(const float4*)&sA[kk * 132 + ty * 8];
      const float4 a1 = *(const float4*)&sA[kk * 132 + ty * 8 + 4];
      const float4 b4 = *(const float4*)&sB[kk * 68 + tx * 4];
      const float ra[8] = {a0.x, a0.y, a0.z, a0.w, a1.x, a1.y, a1.z, a1.w};
      const float rb[4] = {b4.x, b4.y, b4.z, b4.w};
#pragma unroll
      for (int i2 = 0; i2 < 8; i2++)
#pragma unroll
        for (int j2 = 0; j2 < 4; j2++)
          acc[i2][j2] = fmaf(ra[i2], rb[j2], acc[i2][j2]);
    }
    __syncthreads();
  }
#pragma unroll
  for (int i2 = 0; i2 < 8; i2++) {
    int gm = m0 + ty * 8 + i2;
    if (gm >= M) continue;
#pragma unroll
    for (int j2 = 0; j2 < 4; j2++) {
      int gn = n0 + tx * 4 + j2;
      if (gn >= N) continue;
      float v = acc[i2][j2];
      if (bias) v += bias[gn];
      if (ACT == 1) v = fmaxf(v, 0.f);
      C[(size_t)gm * N + gn] = v;
    }
  }
}

// ---------------- 128x128 tiled fp32 GEMM, 8x8 acc (big tall GEMMs) ----------------
template<int AMODE, int ACT>
__global__ __launch_bounds__(256) void gemm3_k(
    const float* __restrict__ A, const float* __restrict__ Bm,
    const float* __restrict__ bias, float* __restrict__ C,
    int M, int N, int K, const float* __restrict__ A2)
{
  __shared__ __align__(16) float sA[16][132];
  __shared__ __align__(16) float sB[16][132];
  const int tid = threadIdx.x;
  const int m0 = blockIdx.y * 128, n0 = blockIdx.x * 128;
  const int tx = tid & 15, ty = tid >> 4;
  const bool fullM = (m0 + 128 <= M);
  const bool fullN = (n0 + 128 <= N);
  const int am = tid >> 1, kq = (tid & 1) * 8;
  const int bk = tid >> 4, bn = (tid & 15) * 8;
  float acc[8][8] = {};
  for (int k0 = 0; k0 < K; k0 += 16) {
    const bool fullK = (k0 + 16 <= K);
    if (AMODE == 0 && fullM && fullK) {
      const float* ap = &A[(size_t)(m0 + am) * K + k0 + kq];
      const float4 v0 = *(const float4*)ap;
      const float4 v1 = *(const float4*)(ap + 4);
      sA[kq + 0][am] = v0.x; sA[kq + 1][am] = v0.y; sA[kq + 2][am] = v0.z; sA[kq + 3][am] = v0.w;
      sA[kq + 4][am] = v1.x; sA[kq + 5][am] = v1.y; sA[kq + 6][am] = v1.z; sA[kq + 7][am] = v1.w;
    } else {
      int gm = m0 + am;
#pragma unroll
      for (int j = 0; j < 8; j++) {
        int gk = k0 + kq + j;
        float va = 0.f;
        if (gm < M && gk < K) {
          if (AMODE == 0) va = A[(size_t)gm * K + gk];
          else            va = (gk < 64) ? A[gm * 64 + gk] : A2[gm * 78 + gk - 64];
        }
        sA[kq + j][am] = va;
      }
    }
    if (fullN && fullK) {
      const float* bp = &Bm[(size_t)(k0 + bk) * N + n0 + bn];
      *(float4*)&sB[bk][bn] = *(const float4*)bp;
      *(float4*)&sB[bk][bn + 4] = *(const float4*)(bp + 4);
    } else {
      int gk2 = k0 + bk;
#pragma unroll
      for (int j = 0; j < 8; j++) {
        int gn = n0 + bn + j;
        float vb = 0.f;
        if (gk2 < K && gn < N) vb = Bm[(size_t)gk2 * N + gn];
        sB[bk][bn + j] = vb;
      }
    }
    __syncthreads();
#pragma unroll
    for (int kk = 0; kk < 16; kk++) {
      const float4 a0 = *(const float4*)&sA[kk][ty * 4];
      const float4 a1 = *(const float4*)&sA[kk][64 + ty * 4];
      const float4 b0 = *(const float4*)&sB[kk][tx * 4];
      const float4 b1 = *(const float4*)&sB[kk][64 + tx * 4];
      const float ra[8] = {a0.x, a0.y, a0.z, a0.w, a1.x, a1.y, a1.z, a1.w};
      const float rb[8] = {b0.x, b0.y, b0.z, b0.w, b1.x, b1.y, b1.z, b1.w};
#pragma unroll
      for (int i = 0; i < 8; i++)
#pragma unroll
        for (int j = 0; j < 8; j++)
          acc[i][j] = fmaf(ra[i], rb[j], acc[i][j]);
    }
    __syncthreads();
  }
#pragma unroll
  for (int i = 0; i < 8; i++) {
    int gm = m0 + (i < 4 ? ty * 4 + i : 64 + ty * 4 + (i - 4));
    if (gm >= M) continue;
#pragma unroll
    for (int j = 0; j < 8; j++) {
      int gn = n0 + (j < 4 ? tx * 4 + j : 64 + tx * 4 + (j - 4));
      if (gn >= N) continue;
      float v = acc[i][j];
      if (bias) v += bias[gn];
      if (ACT == 1) v = fmaxf(v, 0.f);
      C[(size_t)gm * N + gn] = v;
    }
  }
}

// ---------------- BatchNorm (training batch stats over 16384 rows) ----------------
__global__ __launch_bounds__(256) void bn_partial(const float* __restrict__ H,
    float* __restrict__ PS, float* __restrict__ PQ, int C)
{
  int c = blockIdx.x * 64 + (threadIdx.x & 63);
  int rg = threadIdx.x >> 6;
  __shared__ float sS[256], sQ[256];
  float s = 0.f, q = 0.f;
  if (c < C) {
    int base = blockIdx.y * 256 + rg;
    for (int t = 0; t < 64; t++) {
      float v = H[(size_t)(base + 4 * t) * C + c];
      s += v; q += v * v;
    }
  }
  sS[threadIdx.x] = s; sQ[threadIdx.x] = q;
  __syncthreads();
  if (threadIdx.x < 64 && c < C) {
    float ts = sS[threadIdx.x] + sS[threadIdx.x + 64] + sS[threadIdx.x + 128] + sS[threadIdx.x + 192];
    float tq = sQ[threadIdx.x] + sQ[threadIdx.x + 64] + sQ[threadIdx.x + 128] + sQ[threadIdx.x + 192];
    PS[blockIdx.y * C + c] = ts;
    PQ[blockIdx.y * C + c] = tq;
  }
}

__global__ void bn_final(const float* __restrict__ PS, const float* __restrict__ PQ,
                         float* __restrict__ MV, int C)
{
  int c = threadIdx.x;
  if (c >= C) return;
  float s = 0.f, q = 0.f;
  for (int y = 0; y < 64; y++) { s += PS[y * C + c]; q += PQ[y * C + c]; }
  float mean = s * (1.f / 16384.f);
  float var = q * (1.f / 16384.f) - mean * mean;
  MV[c] = mean; MV[256 + c] = var;
}

// act: 1=relu, 2=tanh. xsrc (optional): also copy x into X[:, 78:156] (fused xcopy).
__global__ void bn_norm(const float* __restrict__ IN, float* __restrict__ OUT,
                        const float* __restrict__ MV, const float* __restrict__ g,
                        const float* __restrict__ bb, int C, int ostride, int total, int act,
                        const float* __restrict__ xsrc)
{
  int idx = blockIdx.x * 256 + threadIdx.x;
  if (idx >= total) return;
  int r = idx / C, c = idx - r * C;
  float v = (IN[idx] - MV[c]) * (1.f / sqrtf(MV[256 + c] + 1e-5f)) * g[c] + bb[c];
  v = (act == 1) ? fmaxf(v, 0.f) : tanhf(v);
  OUT[(size_t)r * ostride + c] = v;
  if (xsrc) OUT[(size_t)r * ostride + 78 + c] = xsrc[idx];
}

// ---------------- adjacency: A1/A2/A3 gcn_norm, one block per batch ----------------
__global__ __launch_bounds__(1024) void adj_kernel(const float* __restrict__ adj,
    float* __restrict__ A1o, float* __restrict__ A2o, float* __restrict__ A3o)
{
  int b = blockIdx.x, t = threadIdx.x;
  int i = t >> 5, j = t & 31;
  __shared__ float sA[32][33], sP[32][33];
  __shared__ float sd1[32], sd2[32], sd3[32];
  float a = adj[b * 1024 + t];
  sA[i][j] = a;
  float ah = (i == j) ? fmaxf(a, 1.f) : a;
  float rs = ah;
#pragma unroll
  for (int m = 16; m >= 1; m >>= 1) rs += __shfl_xor(rs, m, 32);
  float di = 1.f / sqrtf(rs);
  if (j == 0) sd1[i] = di;
  __syncthreads();
  A1o[b * 1024 + t] = ah * di * sd1[j];
  float c2 = 0.f;
#pragma unroll
  for (int k = 0; k < 32; k++) c2 += sA[i][k] * sA[k][j];
  float p2 = (c2 > 0.f) ? 1.f : 0.f;
  sP[i][j] = p2;
  float ah2 = (i == j) ? 1.f : p2;
  float rs2 = ah2;
#pragma unroll
  for (int m = 16; m >= 1; m >>= 1) rs2 += __shfl_xor(rs2, m, 32);
  float di2 = 1.f / sqrtf(rs2);
  if (j == 0) sd2[i] = di2;
  __syncthreads();
  A2o[b * 1024 + t] = ah2 * di2 * sd2[j];
  float c3 = 0.f;
#pragma unroll
  for (int k = 0; k < 32; k++) c3 += sP[i][k] * sA[k][j];
  float p3 = (c3 > 0.f) ? 1.f : 0.f;
  float ah3 = (i == j) ? 1.f : p3;
  float rs3 = ah3;
#pragma unroll
  for (int m = 16; m >= 1; m >>= 1) rs3 += __shfl_xor(rs3, m, 32);
  float di3 = 1.f / sqrtf(rs3);
  if (j == 0) sd3[i] = di3;
  __syncthreads();
  A3o[b * 1024 + t] = ah3 * di3 * sd3[j];
}

// ---------------- GCN aggregation ----------------
__global__ __launch_bounds__(64) void agg_kernel(const float* __restrict__ A,
    const float* __restrict__ HW, const float* __restrict__ bias,
    float* __restrict__ OUT, int C)
{
  int b = blockIdx.y;
  int c = blockIdx.x * 64 + threadIdx.x;
  __shared__ float sAd[1024];
  for (int e = threadIdx.x; e < 1024; e += 64) sAd[e] = A[b * 1024 + e];
  __syncthreads();
  if (c >= C) return;
  float hw[32];
  const float* hp = HW + (size_t)b * 32 * C + c;
#pragma unroll
  for (int m = 0; m < 32; m++) hw[m] = hp[(size_t)m * C];
  float bv = bias[c];
#pragma unroll 2
  for (int n = 0; n < 32; n++) {
    float s = bv;
#pragma unroll
    for (int m = 0; m < 32; m++) s = fmaf(sAd[n * 32 + m], hw[m], s);
    OUT[(size_t)b * 32 * C + (size_t)n * C + c] = fmaxf(s, 0.f);
  }
}

// 3-adjacency variant: one launch covers A1/A2/A3 sharing the same HW.
__global__ __launch_bounds__(64) void agg3_kernel(const float* __restrict__ A1,
    const float* __restrict__ A2, const float* __restrict__ A3,
    const float* __restrict__ HW, const float* __restrict__ bias,
    float* __restrict__ O1, float* __restrict__ O2, float* __restrict__ O3, int C)
{
  int b = blockIdx.y;
  int c = blockIdx.x * 64 + threadIdx.x;
  const float* A = (blockIdx.z == 0) ? A1 : ((blockIdx.z == 1) ? A2 : A3);
  float* OUT = (blockIdx.z == 0) ? O1 : ((blockIdx.z == 1) ? O2 : O3);
  __shared__ float sAd[1024];
  for (int e = threadIdx.x; e < 1024; e += 64) sAd[e] = A[b * 1024 + e];
  __syncthreads();
  if (c >= C) return;
  float hw[32];
  const float* hp = HW + (size_t)b * 32 * C + c;
#pragma unroll
  for (int m = 0; m < 32; m++) hw[m] = hp[(size_t)m * C];
  float bv = bias[c];
#pragma unroll 2
  for (int n = 0; n < 32; n++) {
    float s = bv;
#pragma unroll
    for (int m = 0; m < 32; m++) s = fmaf(sAd[n * 32 + m], hw[m], s);
    OUT[(size_t)b * 32 * C + (size_t)n * C + c] = fmaxf(s, 0.f);
  }
}

// ---------------- hg = max over 32 nodes of concat(h3,h5,h6) ----------------
__global__ void hg_kernel(const float* __restrict__ h3, const float* __restrict__ h5,
                          const float* __restrict__ h6, float* __restrict__ HG)
{
  int b = blockIdx.y;
  int c = blockIdx.x * 256 + threadIdx.x;
  if (c >= 1092) return;
  const float* p; int stride;
  if (c < 624)      { p = h3 + (size_t)b * 32 * 624 + c;          stride = 624; }
  else if (c < 936) { p = h5 + (size_t)b * 32 * 312 + (c - 624);  stride = 312; }
  else              { p = h6 + (size_t)b * 32 * 156 + (c - 936);  stride = 156; }
  float m = p[0];
#pragma unroll 4
  for (int n = 1; n < 32; n++) m = fmaxf(m, p[(size_t)n * stride]);
  HG[b * 1092 + c] = m;
}

// ---------------- attention ----------------
__global__ __launch_bounds__(64) void attn_kernel(const float* __restrict__ V,
    float* __restrict__ OUT, int ostride, int ooff)
{
  int r = blockIdx.x, lane = threadIdx.x;
  float v0 = V[r * 128 + lane], v1 = V[r * 128 + 64 + lane];
  float e0 = expf(tanhf(v0)), e1 = expf(tanhf(v1));
  float s = e0 + e1;
#pragma unroll
  for (int m = 32; m >= 1; m >>= 1) s += __shfl_xor(s, m);
  float inv = 1.f / s;
  OUT[r * ostride + ooff + lane] = e0 * inv * v0;
  OUT[r * ostride + ooff + 64 + lane] = e1 * inv * v1;
}

// ---------------- protein tables ----------------
__global__ void mtable_kernel(const float* __restrict__ emb, const float* __restrict__ W10,
    const float* __restrict__ W20, const float* __restrict__ W30, float* __restrict__ M)
{
  int idx = blockIdx.x * 256 + threadIdx.x;
  if (idx >= 3 * 3 * 26 * 96) return;
  int o = idx % 96, tok = (idx / 96) % 26, k = (idx / (96 * 26)) % 3, cv = idx / (96 * 26 * 3);
  const float* W = (cv == 0) ? W10 : ((cv == 1) ? W20 : W30);
  float s = 0.f;
#pragma unroll 4
  for (int i = 0; i < 128; i++) s = fmaf(emb[tok * 128 + i], W[(o * 128 + i) * 3 + k], s);
  M[idx] = s;
}

__global__ void rtable_kernel(const float* __restrict__ M,
    const float* __restrict__ b1, const float* __restrict__ b2, const float* __restrict__ b3,
    float* __restrict__ R1, float* __restrict__ R2, float* __restrict__ R3)
{
  int cv = blockIdx.y;
  int idx = blockIdx.x * 256 + threadIdx.x;
  if (idx >= 17576 * 96) return;
  int o = idx % 96, g = idx / 96;
  int t0 = g / 676, t1 = (g / 26) % 26, t2 = g % 26;
  const float* Mc = M + cv * 3 * 26 * 96;
  float v = ((cv == 0) ? b1 : ((cv == 1) ? b2 : b3))[o];
  v += Mc[(0 * 26 + t0) * 96 + o] + Mc[(1 * 26 + t1) * 96 + o] + Mc[(2 * 26 + t2) * 96 + o];
  float* R = (cv == 0) ? R1 : ((cv == 1) ? R2 : R3);
  R[idx] = fmaxf(v, 0.f);
}

// 3 weight transposes in one launch.
__global__ void wtrans3_kernel(const float* __restrict__ W21, const float* __restrict__ W31,
                               const float* __restrict__ W32,
                               float* __restrict__ O21, float* __restrict__ O31,
                               float* __restrict__ O32)
{
  int e = blockIdx.x * 256 + threadIdx.x;
  if (e >= 96 * 96 * 3) return;
  int job = blockIdx.y;
  const float* W = (job == 0) ? W21 : ((job == 1) ? W31 : W32);
  float* out = (job == 0) ? O21 : ((job == 1) ? O31 : O32);
  int o, i, k;
  if (job < 2) { i = e / 288; int r = e % 288; k = r / 96; o = r % 96; }
  else         { k = e / (96 * 96); i = (e / 96) % 96; o = e % 96; }
  out[e] = W[(o * 96 + i) * 3 + k];
}

// ---------------- fused protein tail: f1 + f2 + conv3(f3), PIPELINED ----------------
// grid (4, 512), 384 threads; 4 tiles of 64 output cols per block, double-buffered sIn.
// While FMA quarter q of tile t runs on sIn[cur], gather iteration q of tile t+1
// (r5 coalesced layout: 24 consecutive threads read one contiguous 384B row-segment)
// issues loads into regs and lands in sIn[nxt]. One barrier per tile.
// COALESCING INVARIANT preserved (r6 lesson: lane=column scatters -> FETCH +40%).
__global__ __launch_bounds__(384) void conv3_fused(const int* __restrict__ target,
    const float* __restrict__ R10,
    const float* __restrict__ N21, const float* __restrict__ b21,
    const float* __restrict__ N31, const float* __restrict__ b31,
    const float* __restrict__ W32t, const float* __restrict__ b32, float* __restrict__ F)
{
  const int b = blockIdx.y;
  const int base = blockIdx.x * 256;   // block covers output cols [base, base+256)
  const int tid = threadIdx.x;
  __shared__ float sIn[2][96 * 67];
  __shared__ int sG[260];
  __shared__ unsigned sR[192];
  const int ngr = min(260, 998 - base);
  if (tid < 192) sR[tid] = 0u;
  for (int p = tid; p < ngr; p += 384) {
    int t0 = target[b * 1000 + base + p];
    int t1 = target[b * 1000 + base + p + 1];
    int t2 = target[b * 1000 + base + p + 2];
    sG[p] = (t0 * 26 + t1) * 26 + t2;
  }
  __syncthreads();

  const int ig = tid % 24, coff = tid / 24, i4 = ig * 4;
  const float4 bb31 = *(const float4*)&b31[i4];
  const float4 bb21 = *(const float4*)&b21[i4];
  float4 v1m = make_float4(0.f, 0.f, 0.f, 0.f);   // f1 max, persists across tiles
  float4 v2m = make_float4(0.f, 0.f, 0.f, 0.f);   // f2 max (pre-relu)
  const int wv = tid >> 6, lane = tid & 63;
  const int obase = __builtin_amdgcn_readfirstlane(wv) * 16;
  float acc[16];

  // staged registers (live across ISSUE..CONSUME; FMAQ between)
  int cl_ = 0; bool do1_ = false, do2_ = false;
  int g0 = 0, g1 = 0, g2 = 0;
  float4 r1a, a0a, a1a, a2a, c0a, c1a, c2a;

#define ISSUE(tt, jj) { \
    const int l0_ = base + 64 * (tt); \
    const int n1_ = min(66, 998 - l0_); \
    const int nc_ = min(66, 996 - l0_); \
    cl_ = coff + 16 * (jj); \
    do1_ = cl_ < n1_; do2_ = cl_ < nc_; \
    if (do1_) { g0 = sG[64 * (tt) + cl_]; \
      r1a = *(const float4*)&R10[(size_t)g0 * 96 + i4]; } \
    if (do2_) { g1 = sG[64 * (tt) + cl_ + 1]; g2 = sG[64 * (tt) + cl_ + 2]; \
      a0a = *(const float4*)&N31[((size_t)g0 * 3 + 0) * 96 + i4]; \
      a1a = *(const float4*)&N31[((size_t)g1 * 3 + 1) * 96 + i4]; \
      a2a = *(const float4*)&N31[((size_t)g2 * 3 + 2) * 96 + i4]; \
      c0a = *(const float4*)&N21[((size_t)g0 * 3 + 0) * 96 + i4]; \
      c1a = *(const float4*)&N21[((size_t)g1 * 3 + 1) * 96 + i4]; \
      c2a = *(const float4*)&N21[((size_t)g2 * 3 + 2) * 96 + i4]; } \
  }

#define CONSUME(dst) { \
    if (do1_) { \
      v1m.x = fmaxf(v1m.x, r1a.x); v1m.y = fmaxf(v1m.y, r1a.y); \
      v1m.z = fmaxf(v1m.z, r1a.z); v1m.w = fmaxf(v1m.w, r1a.w); } \
    if (do2_) { \
      (dst)[(i4 + 0) * 67 + cl_] = fmaxf(bb31.x + a0a.x + a1a.x + a2a.x, 0.f); \
      (dst)[(i4 + 1) * 67 + cl_] = fmaxf(bb31.y + a0a.y + a1a.y + a2a.y, 0.f); \
      (dst)[(i4 + 2) * 67 + cl_] = fmaxf(bb31.z + a0a.z + a1a.z + a2a.z, 0.f); \
      (dst)[(i4 + 3) * 67 + cl_] = fmaxf(bb31.w + a0a.w + a1a.w + a2a.w, 0.f); \
      v2m.x = fmaxf(v2m.x, bb21.x + c0a.x + c1a.x + c2a.x); \
      v2m.y = fmaxf(v2m.y, bb21.y + c0a.y + c1a.y + c2a.y); \
      v2m.z = fmaxf(v2m.z, bb21.z + c0a.z + c1a.z + c2a.z); \
      v2m.w = fmaxf(v2m.w, bb21.w + c0a.w + c1a.w + c2a.w); } \
  }

#define FMAQ(src, q) { \
    _Pragma("unroll 3") \
    for (int k = 0; k < 3; k++) { \
      _Pragma("unroll 4") \
      for (int ii = 0; ii < 24; ii++) { \
        const int i = (q) * 24 + ii; \
        const float xv = (src)[i * 67 + lane + k]; \
        const float* wp = W32t + ((size_t)(k * 96 + i)) * 96 + obase; \
        _Pragma("unroll") \
        for (int jj = 0; jj < 16; jj++) acc[jj] = fmaf(xv, wp[jj], acc[jj]); \
      } \
    } \
  }

  float* cur = sIn[0];
  float* nxt = sIn[1];
  // prologue: gather tile 0 fully into cur
#pragma unroll
  for (int j = 0; j < 5; j++) { ISSUE(0, j); CONSUME(cur); }
  __syncthreads();

#pragma unroll 1
  for (int t = 0; t < 4; t++) {
#pragma unroll
    for (int jj = 0; jj < 16; jj++) acc[jj] = b32[obase + jj];
    if (t < 3) {
      ISSUE(t + 1, 0); FMAQ(cur, 0); CONSUME(nxt);
      ISSUE(t + 1, 1); FMAQ(cur, 1); CONSUME(nxt);
      ISSUE(t + 1, 2); FMAQ(cur, 2); CONSUME(nxt);
      ISSUE(t + 1, 3); FMAQ(cur, 3); CONSUME(nxt);
      ISSUE(t + 1, 4); CONSUME(nxt);
    } else {
      FMAQ(cur, 0); FMAQ(cur, 1); FMAQ(cur, 2); FMAQ(cur, 3);
    }
    // flush conv3 outputs for tile t
    const int noutst = min(64, 994 - (base + 64 * t));
    const bool lok = lane < noutst;
#pragma unroll
    for (int jj = 0; jj < 16; jj++) {
      float v = lok ? fmaxf(acc[jj], 0.f) : 0.f;
#pragma unroll
      for (int m = 32; m >= 1; m >>= 1) v = fmaxf(v, __shfl_xor(v, m));
      if (lane == 0) atomicMax((unsigned int*)&F[b * 288 + 192 + obase + jj], __float_as_uint(v));
    }
    __syncthreads();
    float* tmp = cur; cur = nxt; nxt = tmp;
  }
#undef ISSUE
#undef CONSUME
#undef FMAQ

  // flush f1/f2 maxima (accumulated across all 4 tiles)
  atomicMax(&sR[i4 + 0], __float_as_uint(v1m.x));
  atomicMax(&sR[i4 + 1], __float_as_uint(v1m.y));
  atomicMax(&sR[i4 + 2], __float_as_uint(v1m.z));
  atomicMax(&sR[i4 + 3], __float_as_uint(v1m.w));
  atomicMax(&sR[96 + i4 + 0], __float_as_uint(fmaxf(v2m.x, 0.f)));
  atomicMax(&sR[96 + i4 + 1], __float_as_uint(fmaxf(v2m.y, 0.f)));
  atomicMax(&sR[96 + i4 + 2], __float_as_uint(fmaxf(v2m.z, 0.f)));
  atomicMax(&sR[96 + i4 + 3], __float_as_uint(fmaxf(v2m.w, 0.f)));
  __syncthreads();
  if (tid < 192) {
    int which = tid / 96, i = tid % 96;
    atomicMax((unsigned int*)&F[b * 288 + which * 96 + i], sR[tid]);
  }
}

// ---------------- final row-dot ----------------
__global__ __launch_bounds__(256) void outdot_kernel(const float* __restrict__ X,
    const float* __restrict__ W, const float* __restrict__ bptr, float* __restrict__ out)
{
  int r = blockIdx.x * 4 + (threadIdx.x >> 6);
  int lane = threadIdx.x & 63;
  float s = 0.f;
  for (int j = lane; j < 512; j += 64) s = fmaf(X[(size_t)r * 512 + j], W[j], s);
#pragma unroll
  for (int m = 32; m >= 1; m >>= 1) s += __shfl_xor(s, m);
  if (lane == 0) out[r] = s + bptr[0];
}

// ---------------- host-side dispatch ----------------
static inline void gemm2(hipStream_t st, int AMODE, int ACT,
                         const float* A, const float* B, const float* bias, float* C,
                         int M, int N, int K, const float* A2 = nullptr)
{
  dim3 g((N + 63) / 64, (M + 127) / 128), blk(256);
  if (AMODE == 0 && ACT == 0)      gemm2_k<0, 0><<<g, blk, 0, st>>>(A, B, bias, C, M, N, K, A2);
  else if (AMODE == 0 && ACT == 1) gemm2_k<0, 1><<<g, blk, 0, st>>>(A, B, bias, C, M, N, K, A2);
  else                             gemm2_k<1, 0><<<g, blk, 0, st>>>(A, B, bias, C, M, N, K, A2);
}

static inline void gemm3(hipStream_t st, int AMODE, int ACT,
                         const float* A, const float* B, const float* bias, float* C,
                         int M, int N, int K, const float* A2 = nullptr)
{
  dim3 g((N + 127) / 128, (M + 127) / 128), blk(256);
  if (AMODE == 0 && ACT == 0)      gemm3_k<0, 0><<<g, blk, 0, st>>>(A, B, bias, C, M, N, K, A2);
  else if (AMODE == 0 && ACT == 1) gemm3_k<0, 1><<<g, blk, 0, st>>>(A, B, bias, C, M, N, K, A2);
  else                             gemm3_k<1, 0><<<g, blk, 0, st>>>(A, B, bias, C, M, N, K, A2);
}

// split-K GEMM for small-M heads. N must be a power of two.
static inline void gemm_splitk(hipStream_t st, const float* A, const float* B,
                               const float* bias, float* C, int M, int N, int K,
                               int S, int act, float* PT)
{
  int KS = (K + S - 1) / S;
  dim3 g((N + 63) / 64, (M + 63) / 64, S);
  gemm_sk<<<g, 256, 0, st>>>(A, B, PT, M, N, K, KS);
  int MN = M * N;
  skred_kernel<<<(MN + 255) / 256, 256, 0, st>>>(PT, bias, C, MN, N - 1, S, act);
}

extern "C" void kernel_launch(void* const* d_in, const int* in_sizes, int n_in,
                              void* d_out, int out_size, void* d_ws, size_t ws_size,
                              hipStream_t stream)
{
  (void)in_sizes; (void)n_in; (void)out_size; (void)ws_size;
  const float* x      = (const float*)d_in[0];
  const float* adj    = (const float*)d_in[1];
  const int*   target = (const int*)  d_in[2];
  const float* z      = (const float*)d_in[3];
  const float* dec_W0 = (const float*)d_in[4];
  const float* dec_b0 = (const float*)d_in[5];
  const float* dec_g0 = (const float*)d_in[6];
  const float* dec_be0= (const float*)d_in[7];
  const float* dec_W1 = (const float*)d_in[8];
  const float* dec_b1 = (const float*)d_in[9];
  const float* dec_g1 = (const float*)d_in[10];
  const float* dec_be1= (const float*)d_in[11];
  const float* gW1    = (const float*)d_in[12];
  const float* gb1    = (const float*)d_in[13];
  const float* gW2    = (const float*)d_in[14];
  const float* gb2    = (const float*)d_in[15];
  const float* gW3    = (const float*)d_in[16];
  const float* gb3    = (const float*)d_in[17];
  const float* fcg1_W = (const float*)d_in[18];
  const float* fcg1_b = (const float*)d_in[19];
  const float* fcg2_W = (const float*)d_in[20];
  const float* fcg2_b = (const float*)d_in[21];
  const float* emb    = (const float*)d_in[22];
  const float* c10_W  = (const float*)d_in[23];
  const float* c10_b  = (const float*)d_in[24];
  const float* c20_W  = (const float*)d_in[25];
  const float* c20_b  = (const float*)d_in[26];
  const float* c21_W  = (const float*)d_in[27];
  const float* c21_b  = (const float*)d_in[28];
  const float* c30_W  = (const float*)d_in[29];
  const float* c30_b  = (const float*)d_in[30];
  const float* c31_W  = (const float*)d_in[31];
  const float* c31_b  = (const float*)d_in[32];
  const float* c32_W  = (const float*)d_in[33];
  const float* c32_b  = (const float*)d_in[34];
  const float* prot_W = (const float*)d_in[35];
  const float* prot_b = (const float*)d_in[36];
  const float* fc1_W  = (const float*)d_in[37];
  const float* fc1_b  = (const float*)d_in[38];
  const float* fc2_W  = (const float*)d_in[39];
  const float* fc2_b  = (const float*)d_in[40];
  const float* out_W  = (const float*)d_in[41];
  const float* out_b  = (const float*)d_in[42];
  float* out = (float*)d_out;
  float* ws = (float*)d_ws;

  float* H0   = ws + O_H0;   float* H1P  = ws + O_H1P;  float* X    = ws + O_X;
  float* A1   = ws + O_A1;   float* A2   = ws + O_A2;   float* A3   = ws + O_A3;
  float* XW1  = ws + O_XW1;  float* H1   = ws + O_H1;   float* H4   = ws + O_H4;
  float* H6   = ws + O_H6;   float* H1W2 = ws + O_H1W2; float* H2   = ws + O_H2;
  float* H2W3 = ws + O_H2W3; float* H3   = ws + O_H3;   float* H4W2 = ws + O_H4W2;
  float* H5   = ws + O_H5;   float* HG   = ws + O_HG;   float* FCG1O= ws + O_FCG1O;
  float* Mt   = ws + O_M;    float* F    = ws + O_F;    float* V    = ws + O_V;
  float* XC   = ws + O_XC;   float* FC1O = ws + O_FC1O; float* FC2O = ws + O_FC2O;
  float* PS   = ws + O_PART; float* PQ   = ws + O_PART + 16384;
  float* MV   = ws + O_MV;   float* SK   = ws + O_SK;
  float* R10  = ws + O_R10;  float* R20  = ws + O_R20;  float* R30  = ws + O_R30;
  float* N21  = ws + O_N21;  float* N31  = ws + O_N31;
  float* BT21 = ws + O_BT21; float* BT31 = ws + O_BT31; float* W32T = ws + O_W32T;

  // ---- decoder (frozen cVAE) ----
  gemm2(stream, 1, 0, z, dec_W0, dec_b0, H0, 16384, 256, 142, x);
  bn_partial<<<dim3(4, 64), 256, 0, stream>>>(H0, PS, PQ, 256);
  bn_final<<<1, 256, 0, stream>>>(PS, PQ, MV, 256);
  bn_norm<<<16384, 256, 0, stream>>>(H0, H0, MV, dec_g0, dec_be0, 256, 256, 16384 * 256, 1, nullptr);
  gemm2(stream, 0, 0, H0, dec_W1, dec_b1, H1P, 16384, 78, 256);
  bn_partial<<<dim3(2, 64), 256, 0, stream>>>(H1P, PS, PQ, 78);
  bn_final<<<1, 256, 0, stream>>>(PS, PQ, MV, 78);
  bn_norm<<<4995, 256, 0, stream>>>(H1P, X, MV, dec_g1, dec_be1, 78, 156, 16384 * 78, 2, x);

  // ---- adjacency powers + gcn_norm ----
  adj_kernel<<<512, 1024, 0, stream>>>(adj, A1, A2, A3);

  // ---- GCN stack ----
  gemm3(stream, 0, 0, X, gW1, nullptr, XW1, 16384, 156, 156);
  agg3_kernel<<<dim3(3, 512, 3), 64, 0, stream>>>(A1, A2, A3, XW1, gb1, H1, H4, H6, 156);
  gemm3(stream, 0, 0, H1, gW2, nullptr, H1W2, 16384, 312, 156);
  agg_kernel<<<dim3(5, 512), 64, 0, stream>>>(A1, H1W2, gb2, H2, 312);
  gemm3(stream, 0, 0, H2, gW3, nullptr, H2W3, 16384, 624, 312);
  agg_kernel<<<dim3(10, 512), 64, 0, stream>>>(A1, H2W3, gb3, H3, 624);
  gemm3(stream, 0, 0, H4, gW2, nullptr, H4W2, 16384, 312, 156);
  agg_kernel<<<dim3(5, 512), 64, 0, stream>>>(A2, H4W2, gb2, H5, 312);
  hg_kernel<<<dim3(5, 512), 256, 0, stream>>>(H3, H5, H6, HG);

  // ---- graph head (split-K, partials in dead H0 region) ----
  gemm_splitk(stream, HG, fcg1_W, fcg1_b, FCG1O, 512, 1024, 1092, 4, 1, SK);
  gemm_splitk(stream, FCG1O, fcg2_W, fcg2_b, V, 512, 128, 1024, 8, 0, SK);
  attn_kernel<<<512, 64, 0, stream>>>(V, XC, 256, 0);

  // ---- protein branch ----
  hipMemsetAsync(F, 0, 512 * 288 * sizeof(float), stream);
  mtable_kernel<<<264, 256, 0, stream>>>(emb, c10_W, c20_W, c30_W, Mt);
  rtable_kernel<<<dim3(6591, 3), 256, 0, stream>>>(Mt, c10_b, c20_b, c30_b, R10, R20, R30);
  wtrans3_kernel<<<dim3(108, 3), 256, 0, stream>>>(c21_W, c31_W, c32_W, BT21, BT31, W32T);
  gemm3(stream, 0, 0, R20, BT21, nullptr, N21, 17576, 288, 96);
  gemm3(stream, 0, 0, R30, BT31, nullptr, N31, 17576, 288, 96);
  conv3_fused<<<dim3(4, 512), 384, 0, stream>>>(target, R10, N21, c21_b, N31, c31_b, W32T, c32_b, F);
  gemm_splitk(stream, F, prot_W, prot_b, V, 512, 128, 288, 4, 0, SK);
  attn_kernel<<<512, 64, 0, stream>>>(V, XC, 256, 128);

  // ---- final MLP (split-K) ----
  gemm_splitk(stream, XC, fc1_W, fc1_b, FC1O, 512, 1024, 256, 2, 1, SK);
  gemm_splitk(stream, FC1O, fc2_W, fc2_b, FC2O, 512, 512, 1024, 4, 1, SK);
  outdot_kernel<<<128, 256, 0, stream>>>(FC2O, out_W, out_b, out);
}

// Round 10
// 1197.093 us; speedup vs baseline: 1.4812x; 1.4812x over previous
//
#include <hip/hip_runtime.h>

// ---------------- workspace offsets (in floats) ----------------
static constexpr size_t O_H0    = 0;          // 16384*256 (also split-K partials later)
static constexpr size_t O_H1P   = 4194304;    // 16384*78
static constexpr size_t O_X     = 5473216;    // 16384*156
static constexpr size_t O_A1    = 8029120;    // 512*1024
static constexpr size_t O_A2    = 8553408;
static constexpr size_t O_A3    = 9077696;
static constexpr size_t O_H4    = 9601984;    // 16384*156
static constexpr size_t O_H6    = 12157888;   // (unused now)
static constexpr size_t O_H1W2  = 14713792;   // 16384*312
static constexpr size_t O_H2    = 19825600;   // 16384*312
static constexpr size_t O_H2W3  = 24937408;   // 16384*624
static constexpr size_t O_H3    = 35161024;   // (unused now)
static constexpr size_t O_HG    = 45384640;   // 512*1092
static constexpr size_t O_FCG1O = 45943744;   // 512*1024
static constexpr size_t O_M     = 46468032;   // 3*3*26*96
static constexpr size_t O_F     = 46535424;   // 512*288
static constexpr size_t O_V     = 46682880;   // 512*128
static constexpr size_t O_XC    = 46748416;   // 512*256
static constexpr size_t O_FC1O  = 46879488;   // 512*1024
static constexpr size_t O_FC2O  = 47403776;   // 512*512
static constexpr size_t O_PART  = 47665920;   // 2*64*256
static constexpr size_t O_MV    = 47698688;   // 1024
static constexpr size_t O_BT21  = 47699712;   // 96*96*3
static constexpr size_t O_BT31  = 47727360;
static constexpr size_t O_W32T  = 47755008;   // end 47782656 floats = 191.1 MB
// aliases (sequentially dead regions reused):
static constexpr size_t O_XW1  = O_H0;             // after decoder done
static constexpr size_t O_SK   = O_H0;             // split-K partials (head phase)
static constexpr size_t O_H1   = O_X;              // after XW1 GEMM
static constexpr size_t O_H4W2 = O_H1W2;           // after h2 agg
static constexpr size_t O_R10  = O_H1W2;           // protein phase (after h5 aggmax)
static constexpr size_t O_R20  = O_H1W2 + 1687296;
static constexpr size_t O_R30  = O_H1W2 + 3374592;
static constexpr size_t O_N21  = O_H2W3;           // protein phase (after h3 aggmax)
static constexpr size_t O_N31  = O_H2W3 + 5061888;

// ---------------- split-K 64x64 GEMM: writes partials, no bias/act ----------------
// float4 fast-path staging for interior tiles (all call sites: K%4==0, N%4==0).
__global__ __launch_bounds__(256) void gemm_sk(
    const float* __restrict__ A, const float* __restrict__ Bm,
    float* __restrict__ PT, int M, int N, int K, int KS)
{
  __shared__ __align__(16) float sA[16 * 68];
  __shared__ __align__(16) float sB[16 * 68];
  const int tid = threadIdx.x;
  const int m0 = blockIdx.y * 64, n0 = blockIdx.x * 64;
  const int kb = blockIdx.z * KS;
  const int ke = min(K, kb + KS);
  const int tx = tid & 15, ty = tid >> 4;
  const bool fullM = (m0 + 64 <= M), fullN = (n0 + 64 <= N);
  float acc[4][4] = {};
  for (int k0 = kb; k0 < ke; k0 += 16) {
    const bool fullK = (k0 + 16 <= ke);
    if (fullM && fullK) {
      const int am = tid >> 2, ak = (tid & 3) * 4;
      const float4 v = *(const float4*)&A[(size_t)(m0 + am) * K + k0 + ak];
      sA[(ak + 0) * 68 + am] = v.x; sA[(ak + 1) * 68 + am] = v.y;
      sA[(ak + 2) * 68 + am] = v.z; sA[(ak + 3) * 68 + am] = v.w;
    } else {
#pragma unroll
      for (int s2 = 0; s2 < 4; s2++) {
        int idx = tid + s2 * 256;
        int am = idx >> 4, ak = idx & 15;
        int gm = m0 + am, gk = k0 + ak;
        float va = 0.f;
        if (gm < M && gk < ke) va = A[(size_t)gm * K + gk];
        sA[ak * 68 + am] = va;
      }
    }
    if (fullN && fullK) {
      const int bk = tid >> 4, bn4 = (tid & 15) * 4;
      *(float4*)&sB[bk * 68 + bn4] = *(const float4*)&Bm[(size_t)(k0 + bk) * N + n0 + bn4];
    } else {
#pragma unroll
      for (int s2 = 0; s2 < 4; s2++) {
        int idx = tid + s2 * 256;
        int bk2 = idx >> 6, bn = idx & 63;
        int gk2 = k0 + bk2, gn = n0 + bn;
        float vb = 0.f;
        if (gk2 < ke && gn < N) vb = Bm[(size_t)gk2 * N + gn];
        sB[bk2 * 68 + bn] = vb;
      }
    }
    __syncthreads();
#pragma unroll
    for (int kk = 0; kk < 16; kk++) {
      const float4 a4 = *(const float4*)&sA[kk * 68 + ty * 4];
      const float4 b4 = *(const float4*)&sB[kk * 68 + tx * 4];
      const float ra[4] = {a4.x, a4.y, a4.z, a4.w};
      const float rb[4] = {b4.x, b4.y, b4.z, b4.w};
#pragma unroll
      for (int i2 = 0; i2 < 4; i2++)
#pragma unroll
        for (int j2 = 0; j2 < 4; j2++)
          acc[i2][j2] = fmaf(ra[i2], rb[j2], acc[i2][j2]);
    }
    __syncthreads();
  }
  float* P = PT + (size_t)blockIdx.z * M * N;
#pragma unroll
  for (int i2 = 0; i2 < 4; i2++) {
    int gm = m0 + ty * 4 + i2;
    if (gm >= M) continue;
#pragma unroll
    for (int j2 = 0; j2 < 4; j2++) {
      int gn = n0 + tx * 4 + j2;
      if (gn >= N) continue;
      P[(size_t)gm * N + gn] = acc[i2][j2];
    }
  }
}

// reduce split-K partials (deterministic slice order). nmask = N-1 (N power of two).
__global__ void skred_kernel(const float* __restrict__ PT, const float* __restrict__ bias,
                             float* __restrict__ C, int MN, int nmask, int S, int act)
{
  int i = blockIdx.x * 256 + threadIdx.x;
  if (i >= MN) return;
  float s = 0.f;
  for (int z = 0; z < S; z++) s += PT[(size_t)z * MN + i];
  if (bias) s += bias[i & nmask];
  if (act) s = fmaxf(s, 0.f);
  C[i] = s;
}

// ---------------- 128x64 tiled fp32 GEMM, 8x4 acc (tall-M cases) ----------------
template<int AMODE, int ACT>
__global__ __launch_bounds__(256) void gemm2_k(
    const float* __restrict__ A, const float* __restrict__ Bm,
    const float* __restrict__ bias, float* __restrict__ C,
    int M, int N, int K, const float* __restrict__ A2)
{
  __shared__ __align__(16) float sA[16 * 132];  // [k][m]
  __shared__ __align__(16) float sB[16 * 68];   // [k][n]
  const int tid = threadIdx.x;
  const int m0 = blockIdx.y * 128, n0 = blockIdx.x * 64;
  const int tx = tid & 15, ty = tid >> 4;
  float acc[8][4] = {};
  for (int k0 = 0; k0 < K; k0 += 16) {
#pragma unroll
    for (int s2 = 0; s2 < 2; s2++) {
      int idx = tid + s2 * 256;
      int am = idx >> 2, kq = idx & 3;
      int gm = m0 + am;
#pragma unroll
      for (int j = 0; j < 4; j++) {
        int gk = k0 + kq * 4 + j;
        float va = 0.f;
        if (gm < M && gk < K) {
          if (AMODE == 0) va = A[(size_t)gm * K + gk];
          else            va = (gk < 64) ? A[gm * 64 + gk] : A2[gm * 78 + gk - 64];
        }
        sA[(kq * 4 + j) * 132 + am] = va;
      }
    }
    {
      int bk = tid >> 4, bn4 = tid & 15;
      int gk2 = k0 + bk;
#pragma unroll
      for (int j = 0; j < 4; j++) {
        int gn = n0 + bn4 * 4 + j;
        float vb = 0.f;
        if (gk2 < K && gn < N) vb = Bm[(size_t)gk2 * N + gn];
        sB[bk * 68 + bn4 * 4 + j] = vb;
      }
    }
    __syncthreads();
#pragma unroll
    for (int kk = 0; kk < 16; kk++) {
      const float4 a0 = *(const float4*)&sA[kk * 132 + ty * 8];
      const float4 a1 = *(const float4*)&sA[kk * 132 + ty * 8 + 4];
      const float4 b4 = *(const float4*)&sB[kk * 68 + tx * 4];
      const float ra[8] = {a0.x, a0.y, a0.z, a0.w, a1.x, a1.y, a1.z, a1.w};
      const float rb[4] = {b4.x, b4.y, b4.z, b4.w};
#pragma unroll
      for (int i2 = 0; i2 < 8; i2++)
#pragma unroll
        for (int j2 = 0; j2 < 4; j2++)
          acc[i2][j2] = fmaf(ra[i2], rb[j2], acc[i2][j2]);
    }
    __syncthreads();
  }
#pragma unroll
  for (int i2 = 0; i2 < 8; i2++) {
    int gm = m0 + ty * 8 + i2;
    if (gm >= M) continue;
#pragma unroll
    for (int j2 = 0; j2 < 4; j2++) {
      int gn = n0 + tx * 4 + j2;
      if (gn >= N) continue;
      float v = acc[i2][j2];
      if (bias) v += bias[gn];
      if (ACT == 1) v = fmaxf(v, 0.f);
      C[(size_t)gm * N + gn] = v;
    }
  }
}

// ---------------- 128x128 tiled fp32 GEMM, 8x8 acc (big tall GEMMs) ----------------
template<int AMODE, int ACT>
__global__ __launch_bounds__(256) void gemm3_k(
    const float* __restrict__ A, const float* __restrict__ Bm,
    const float* __restrict__ bias, float* __restrict__ C,
    int M, int N, int K, const float* __restrict__ A2)
{
  __shared__ __align__(16) float sA[16][132];
  __shared__ __align__(16) float sB[16][132];
  const int tid = threadIdx.x;
  const int m0 = blockIdx.y * 128, n0 = blockIdx.x * 128;
  const int tx = tid & 15, ty = tid >> 4;
  const bool fullM = (m0 + 128 <= M);
  const bool fullN = (n0 + 128 <= N);
  const int am = tid >> 1, kq = (tid & 1) * 8;
  const int bk = tid >> 4, bn = (tid & 15) * 8;
  float acc[8][8] = {};
  for (int k0 = 0; k0 < K; k0 += 16) {
    const bool fullK = (k0 + 16 <= K);
    if (AMODE == 0 && fullM && fullK) {
      const float* ap = &A[(size_t)(m0 + am) * K + k0 + kq];
      const float4 v0 = *(const float4*)ap;
      const float4 v1 = *(const float4*)(ap + 4);
      sA[kq + 0][am] = v0.x; sA[kq + 1][am] = v0.y; sA[kq + 2][am] = v0.z; sA[kq + 3][am] = v0.w;
      sA[kq + 4][am] = v1.x; sA[kq + 5][am] = v1.y; sA[kq + 6][am] = v1.z; sA[kq + 7][am] = v1.w;
    } else {
      int gm = m0 + am;
#pragma unroll
      for (int j = 0; j < 8; j++) {
        int gk = k0 + kq + j;
        float va = 0.f;
        if (gm < M && gk < K) {
          if (AMODE == 0) va = A[(size_t)gm * K + gk];
          else            va = (gk < 64) ? A[gm * 64 + gk] : A2[gm * 78 + gk - 64];
        }
        sA[kq + j][am] = va;
      }
    }
    if (fullN && fullK) {
      const float* bp = &Bm[(size_t)(k0 + bk) * N + n0 + bn];
      *(float4*)&sB[bk][bn] = *(const float4*)bp;
      *(float4*)&sB[bk][bn + 4] = *(const float4*)(bp + 4);
    } else {
      int gk2 = k0 + bk;
#pragma unroll
      for (int j = 0; j < 8; j++) {
        int gn = n0 + bn + j;
        float vb = 0.f;
        if (gk2 < K && gn < N) vb = Bm[(size_t)gk2 * N + gn];
        sB[bk][bn + j] = vb;
      }
    }
    __syncthreads();
#pragma unroll
    for (int kk = 0; kk < 16; kk++) {
      const float4 a0 = *(const float4*)&sA[kk][ty * 4];
      const float4 a1 = *(const float4*)&sA[kk][64 + ty * 4];
      const float4 b0 = *(const float4*)&sB[kk][tx * 4];
      const float4 b1 = *(const float4*)&sB[kk][64 + tx * 4];
      const float ra[8] = {a0.x, a0.y, a0.z, a0.w, a1.x, a1.y, a1.z, a1.w};
      const float rb[8] = {b0.x, b0.y, b0.z, b0.w, b1.x, b1.y, b1.z, b1.w};
#pragma unroll
      for (int i = 0; i < 8; i++)
#pragma unroll
        for (int j = 0; j < 8; j++)
          acc[i][j] = fmaf(ra[i], rb[j], acc[i][j]);
    }
    __syncthreads();
  }
#pragma unroll
  for (int i = 0; i < 8; i++) {
    int gm = m0 + (i < 4 ? ty * 4 + i : 64 + ty * 4 + (i - 4));
    if (gm >= M) continue;
#pragma unroll
    for (int j = 0; j < 8; j++) {
      int gn = n0 + (j < 4 ? tx * 4 + j : 64 + tx * 4 + (j - 4));
      if (gn >= N) continue;
      float v = acc[i][j];
      if (bias) v += bias[gn];
      if (ACT == 1) v = fmaxf(v, 0.f);
      C[(size_t)gm * N + gn] = v;
    }
  }
}

// ---------------- BatchNorm (training batch stats over 16384 rows) ----------------
__global__ __launch_bounds__(256) void bn_partial(const float* __restrict__ H,
    float* __restrict__ PS, float* __restrict__ PQ, int C)
{
  int c = blockIdx.x * 64 + (threadIdx.x & 63);
  int rg = threadIdx.x >> 6;
  __shared__ float sS[256], sQ[256];
  float s = 0.f, q = 0.f;
  if (c < C) {
    int base = blockIdx.y * 256 + rg;
    for (int t = 0; t < 64; t++) {
      float v = H[(size_t)(base + 4 * t) * C + c];
      s += v; q += v * v;
    }
  }
  sS[threadIdx.x] = s; sQ[threadIdx.x] = q;
  __syncthreads();
  if (threadIdx.x < 64 && c < C) {
    float ts = sS[threadIdx.x] + sS[threadIdx.x + 64] + sS[threadIdx.x + 128] + sS[threadIdx.x + 192];
    float tq = sQ[threadIdx.x] + sQ[threadIdx.x + 64] + sQ[threadIdx.x + 128] + sQ[threadIdx.x + 192];
    PS[blockIdx.y * C + c] = ts;
    PQ[blockIdx.y * C + c] = tq;
  }
}

__global__ void bn_final(const float* __restrict__ PS, const float* __restrict__ PQ,
                         float* __restrict__ MV, int C)
{
  int c = threadIdx.x;
  if (c >= C) return;
  float s = 0.f, q = 0.f;
  for (int y = 0; y < 64; y++) { s += PS[y * C + c]; q += PQ[y * C + c]; }
  float mean = s * (1.f / 16384.f);
  float var = q * (1.f / 16384.f) - mean * mean;
  MV[c] = mean; MV[256 + c] = var;
}

// act: 1=relu, 2=tanh. xsrc (optional): also copy x into X[:, 78:156] (fused xcopy).
__global__ void bn_norm(const float* __restrict__ IN, float* __restrict__ OUT,
                        const float* __restrict__ MV, const float* __restrict__ g,
                        const float* __restrict__ bb, int C, int ostride, int total, int act,
                        const float* __restrict__ xsrc)
{
  int idx = blockIdx.x * 256 + threadIdx.x;
  if (idx >= total) return;
  int r = idx / C, c = idx - r * C;
  float v = (IN[idx] - MV[c]) * (1.f / sqrtf(MV[256 + c] + 1e-5f)) * g[c] + bb[c];
  v = (act == 1) ? fmaxf(v, 0.f) : tanhf(v);
  OUT[(size_t)r * ostride + c] = v;
  if (xsrc) OUT[(size_t)r * ostride + 78 + c] = xsrc[idx];
}

// ---------------- adjacency: A1/A2/A3 gcn_norm, one block per batch ----------------
__global__ __launch_bounds__(1024) void adj_kernel(const float* __restrict__ adj,
    float* __restrict__ A1o, float* __restrict__ A2o, float* __restrict__ A3o)
{
  int b = blockIdx.x, t = threadIdx.x;
  int i = t >> 5, j = t & 31;
  __shared__ float sA[32][33], sP[32][33];
  __shared__ float sd1[32], sd2[32], sd3[32];
  float a = adj[b * 1024 + t];
  sA[i][j] = a;
  float ah = (i == j) ? fmaxf(a, 1.f) : a;
  float rs = ah;
#pragma unroll
  for (int m = 16; m >= 1; m >>= 1) rs += __shfl_xor(rs, m, 32);
  float di = 1.f / sqrtf(rs);
  if (j == 0) sd1[i] = di;
  __syncthreads();
  A1o[b * 1024 + t] = ah * di * sd1[j];
  float c2 = 0.f;
#pragma unroll
  for (int k = 0; k < 32; k++) c2 += sA[i][k] * sA[k][j];
  float p2 = (c2 > 0.f) ? 1.f : 0.f;
  sP[i][j] = p2;
  float ah2 = (i == j) ? 1.f : p2;
  float rs2 = ah2;
#pragma unroll
  for (int m = 16; m >= 1; m >>= 1) rs2 += __shfl_xor(rs2, m, 32);
  float di2 = 1.f / sqrtf(rs2);
  if (j == 0) sd2[i] = di2;
  __syncthreads();
  A2o[b * 1024 + t] = ah2 * di2 * sd2[j];
  float c3 = 0.f;
#pragma unroll
  for (int k = 0; k < 32; k++) c3 += sP[i][k] * sA[k][j];
  float p3 = (c3 > 0.f) ? 1.f : 0.f;
  float ah3 = (i == j) ? 1.f : p3;
  float rs3 = ah3;
#pragma unroll
  for (int m = 16; m >= 1; m >>= 1) rs3 += __shfl_xor(rs3, m, 32);
  float di3 = 1.f / sqrtf(rs3);
  if (j == 0) sd3[i] = di3;
  __syncthreads();
  A3o[b * 1024 + t] = ah3 * di3 * sd3[j];
}

// ---------------- GCN aggregation (normal write) ----------------
__global__ __launch_bounds__(64) void agg_kernel(const float* __restrict__ A,
    const float* __restrict__ HW, const float* __restrict__ bias,
    float* __restrict__ OUT, int C)
{
  int b = blockIdx.y;
  int c = blockIdx.x * 64 + threadIdx.x;
  __shared__ float sAd[1024];
  for (int e = threadIdx.x; e < 1024; e += 64) sAd[e] = A[b * 1024 + e];
  __syncthreads();
  if (c >= C) return;
  float hw[32];
  const float* hp = HW + (size_t)b * 32 * C + c;
#pragma unroll
  for (int m = 0; m < 32; m++) hw[m] = hp[(size_t)m * C];
  float bv = bias[c];
#pragma unroll 2
  for (int n = 0; n < 32; n++) {
    float s = bv;
#pragma unroll
    for (int m = 0; m < 32; m++) s = fmaf(sAd[n * 32 + m], hw[m], s);
    OUT[(size_t)b * 32 * C + (size_t)n * C + c] = fmaxf(s, 0.f);
  }
}

// ---------------- GCN aggregation + gmp fused: HG[b, off+c] = relu(max_n (A@HW+b)) ----------------
// h3/h5/h6 feed ONLY the global max pool -> never materialize them.
// max_n relu(x) == relu(max_n x) (relu monotone). Each (b,c) owned by one block: plain store.
__global__ __launch_bounds__(64) void aggmax_kernel(const float* __restrict__ A,
    const float* __restrict__ HW, const float* __restrict__ bias,
    float* __restrict__ HG, int C, int off)
{
  int b = blockIdx.y;
  int c = blockIdx.x * 64 + threadIdx.x;
  __shared__ float sAd[1024];
  for (int e = threadIdx.x; e < 1024; e += 64) sAd[e] = A[b * 1024 + e];
  __syncthreads();
  if (c >= C) return;
  float hw[32];
  const float* hp = HW + (size_t)b * 32 * C + c;
#pragma unroll
  for (int m = 0; m < 32; m++) hw[m] = hp[(size_t)m * C];
  float bv = bias[c];
  float mx = -3.4e38f;
#pragma unroll 2
  for (int n = 0; n < 32; n++) {
    float s = bv;
#pragma unroll
    for (int m = 0; m < 32; m++) s = fmaf(sAd[n * 32 + m], hw[m], s);
    mx = fmaxf(mx, s);
  }
  HG[b * 1092 + off + c] = fmaxf(mx, 0.f);
}

// 3-way variant over XW1: z=0 -> H1 (A1, normal), z=1 -> H4 (A2, normal), z=2 -> h6 max (A3 -> HG+936)
__global__ __launch_bounds__(64) void agg3_kernel(const float* __restrict__ A1,
    const float* __restrict__ A2, const float* __restrict__ A3,
    const float* __restrict__ HW, const float* __restrict__ bias,
    float* __restrict__ O1, float* __restrict__ O2, float* __restrict__ HG, int C)
{
  int b = blockIdx.y;
  int c = blockIdx.x * 64 + threadIdx.x;
  const int zz = blockIdx.z;
  const float* A = (zz == 0) ? A1 : ((zz == 1) ? A2 : A3);
  __shared__ float sAd[1024];
  for (int e = threadIdx.x; e < 1024; e += 64) sAd[e] = A[b * 1024 + e];
  __syncthreads();
  if (c >= C) return;
  float hw[32];
  const float* hp = HW + (size_t)b * 32 * C + c;
#pragma unroll
  for (int m = 0; m < 32; m++) hw[m] = hp[(size_t)m * C];
  float bv = bias[c];
  if (zz < 2) {
    float* OUT = (zz == 0) ? O1 : O2;
#pragma unroll 2
    for (int n = 0; n < 32; n++) {
      float s = bv;
#pragma unroll
      for (int m = 0; m < 32; m++) s = fmaf(sAd[n * 32 + m], hw[m], s);
      OUT[(size_t)b * 32 * C + (size_t)n * C + c] = fmaxf(s, 0.f);
    }
  } else {
    float mx = -3.4e38f;
#pragma unroll 2
    for (int n = 0; n < 32; n++) {
      float s = bv;
#pragma unroll
      for (int m = 0; m < 32; m++) s = fmaf(sAd[n * 32 + m], hw[m], s);
      mx = fmaxf(mx, s);
    }
    HG[b * 1092 + 936 + c] = fmaxf(mx, 0.f);
  }
}

// ---------------- attention ----------------
__global__ __launch_bounds__(64) void attn_kernel(const float* __restrict__ V,
    float* __restrict__ OUT, int ostride, int ooff)
{
  int r = blockIdx.x, lane = threadIdx.x;
  float v0 = V[r * 128 + lane], v1 = V[r * 128 + 64 + lane];
  float e0 = expf(tanhf(v0)), e1 = expf(tanhf(v1));
  float s = e0 + e1;
#pragma unroll
  for (int m = 32; m >= 1; m >>= 1) s += __shfl_xor(s, m);
  float inv = 1.f / s;
  OUT[r * ostride + ooff + lane] = e0 * inv * v0;
  OUT[r * ostride + ooff + 64 + lane] = e1 * inv * v1;
}

// ---------------- protein tables ----------------
__global__ void mtable_kernel(const float* __restrict__ emb, const float* __restrict__ W10,
    const float* __restrict__ W20, const float* __restrict__ W30, float* __restrict__ M)
{
  int idx = blockIdx.x * 256 + threadIdx.x;
  if (idx >= 3 * 3 * 26 * 96) return;
  int o = idx % 96, tok = (idx / 96) % 26, k = (idx / (96 * 26)) % 3, cv = idx / (96 * 26 * 3);
  const float* W = (cv == 0) ? W10 : ((cv == 1) ? W20 : W30);
  float s = 0.f;
#pragma unroll 4
  for (int i = 0; i < 128; i++) s = fmaf(emb[tok * 128 + i], W[(o * 128 + i) * 3 + k], s);
  M[idx] = s;
}

__global__ void rtable_kernel(const float* __restrict__ M,
    const float* __restrict__ b1, const float* __restrict__ b2, const float* __restrict__ b3,
    float* __restrict__ R1, float* __restrict__ R2, float* __restrict__ R3)
{
  int cv = blockIdx.y;
  int idx = blockIdx.x * 256 + threadIdx.x;
  if (idx >= 17576 * 96) return;
  int o = idx % 96, g = idx / 96;
  int t0 = g / 676, t1 = (g / 26) % 26, t2 = g % 26;
  const float* Mc = M + cv * 3 * 26 * 96;
  float v = ((cv == 0) ? b1 : ((cv == 1) ? b2 : b3))[o];
  v += Mc[(0 * 26 + t0) * 96 + o] + Mc[(1 * 26 + t1) * 96 + o] + Mc[(2 * 26 + t2) * 96 + o];
  float* R = (cv == 0) ? R1 : ((cv == 1) ? R2 : R3);
  R[idx] = fmaxf(v, 0.f);
}

// 3 weight transposes in one launch.
__global__ void wtrans3_kernel(const float* __restrict__ W21, const float* __restrict__ W31,
                               const float* __restrict__ W32,
                               float* __restrict__ O21, float* __restrict__ O31,
                               float* __restrict__ O32)
{
  int e = blockIdx.x * 256 + threadIdx.x;
  if (e >= 96 * 96 * 3) return;
  int job = blockIdx.y;
  const float* W = (job == 0) ? W21 : ((job == 1) ? W31 : W32);
  float* out = (job == 0) ? O21 : ((job == 1) ? O31 : O32);
  int o, i, k;
  if (job < 2) { i = e / 288; int r = e % 288; k = r / 96; o = r % 96; }
  else         { k = e / (96 * 96); i = (e / 96) % 96; o = e % 96; }
  out[e] = W[(o * 96 + i) * 3 + k];
}

// ---------------- fused protein tail: f1 + f2 + conv3(f3), float4 gather (r7 = 470us) ----------------
// grid (16, 512), 384 threads = 24 channel-groups(4ch) x 16 col-offsets.
// COALESCING INVARIANT: 24 consecutive threads (same coff) read one contiguous 384B table row.
// Do NOT switch to lane=column layout (r6: FETCH +40%, 450->759us).
// Do NOT software-pipeline with per-phase vmcnt waits / dbuf LDS (r9: occ 50%->17%, 470->990us).
// This structure (5 blocks/CU, whole gather loop in flight) is the measured local optimum.
__global__ __launch_bounds__(384) void conv3_fused(const int* __restrict__ target,
    const float* __restrict__ R10,
    const float* __restrict__ N21, const float* __restrict__ b21,
    const float* __restrict__ N31, const float* __restrict__ b31,
    const float* __restrict__ W32t, const float* __restrict__ b32, float* __restrict__ F)
{
  int b = blockIdx.y, tile = blockIdx.x;
  int l0 = tile * 64;
  int tid = threadIdx.x;
  __shared__ float sIn[96 * 67];   // layer-2 (c31 path) tile [i][c], pitch 67
  __shared__ int sG[68];
  __shared__ unsigned sR[192];     // [0:96) f1 max, [96:192) f2 max
  int ncols = min(66, 996 - l0);   // conv2-output cols (also f2 positions here)
  int n1    = min(66, 998 - l0);   // f1 positions in this tile
  int nouts = min(64, 994 - l0);   // conv3 outputs this tile
  int ng    = min(68, 998 - l0);   // grams to stage
  if (tid < 192) sR[tid] = 0u;
  for (int p = tid; p < ng; p += 384) {
    int t0 = target[b * 1000 + l0 + p];
    int t1 = target[b * 1000 + l0 + p + 1];
    int t2 = target[b * 1000 + l0 + p + 2];
    sG[p] = (t0 * 26 + t1) * 26 + t2;
  }
  __syncthreads();
  // gather phase: thread -> 4 consecutive channels, cols stride 16. All table reads float4.
  {
    int ig = tid % 24;
    int coff = tid / 24;            // 0..15
    int i4 = ig * 4;
    float4 v1m = make_float4(0.f, 0.f, 0.f, 0.f);
    float4 v2m = make_float4(0.f, 0.f, 0.f, 0.f);
    const float4 bb31 = *(const float4*)&b31[i4];
    const float4 bb21 = *(const float4*)&b21[i4];
    for (int c = coff; c < n1; c += 16) {
      float4 r1 = *(const float4*)&R10[(size_t)sG[c] * 96 + i4];
      v1m.x = fmaxf(v1m.x, r1.x); v1m.y = fmaxf(v1m.y, r1.y);
      v1m.z = fmaxf(v1m.z, r1.z); v1m.w = fmaxf(v1m.w, r1.w);
      if (c < ncols) {
        size_t r0 = (size_t)sG[c] * 3 + 0;
        size_t r1i = (size_t)sG[c + 1] * 3 + 1;
        size_t r2 = (size_t)sG[c + 2] * 3 + 2;
        float4 a0 = *(const float4*)&N31[r0 * 96 + i4];
        float4 a1 = *(const float4*)&N31[r1i * 96 + i4];
        float4 a2 = *(const float4*)&N31[r2 * 96 + i4];
        sIn[(i4 + 0) * 67 + c] = fmaxf(bb31.x + a0.x + a1.x + a2.x, 0.f);
        sIn[(i4 + 1) * 67 + c] = fmaxf(bb31.y + a0.y + a1.y + a2.y, 0.f);
        sIn[(i4 + 2) * 67 + c] = fmaxf(bb31.z + a0.z + a1.z + a2.z, 0.f);
        sIn[(i4 + 3) * 67 + c] = fmaxf(bb31.w + a0.w + a1.w + a2.w, 0.f);
        float4 c0 = *(const float4*)&N21[r0 * 96 + i4];
        float4 c1 = *(const float4*)&N21[r1i * 96 + i4];
        float4 c2 = *(const float4*)&N21[r2 * 96 + i4];
        v2m.x = fmaxf(v2m.x, bb21.x + c0.x + c1.x + c2.x);
        v2m.y = fmaxf(v2m.y, bb21.y + c0.y + c1.y + c2.y);
        v2m.z = fmaxf(v2m.z, bb21.z + c0.z + c1.z + c2.z);
        v2m.w = fmaxf(v2m.w, bb21.w + c0.w + c1.w + c2.w);
      }
    }
    // v2m components may be negative pre-relu; clamp before uint-ordered max
    atomicMax(&sR[i4 + 0], __float_as_uint(v1m.x));
    atomicMax(&sR[i4 + 1], __float_as_uint(v1m.y));
    atomicMax(&sR[i4 + 2], __float_as_uint(v1m.z));
    atomicMax(&sR[i4 + 3], __float_as_uint(v1m.w));
    atomicMax(&sR[96 + i4 + 0], __float_as_uint(fmaxf(v2m.x, 0.f)));
    atomicMax(&sR[96 + i4 + 1], __float_as_uint(fmaxf(v2m.y, 0.f)));
    atomicMax(&sR[96 + i4 + 2], __float_as_uint(fmaxf(v2m.z, 0.f)));
    atomicMax(&sR[96 + i4 + 3], __float_as_uint(fmaxf(v2m.w, 0.f)));
  }
  __syncthreads();
  if (tid < 192) {
    int which = tid / 96, i = tid % 96;
    atomicMax((unsigned int*)&F[b * 288 + which * 96 + i], sR[tid]);
  }
  // conv3 FMA phase: 6 waves x 16 outs; lane = column.
  int wv = __builtin_amdgcn_readfirstlane(tid >> 6);
  int lane = tid & 63;
  int obase = wv * 16;
  float acc[16];
#pragma unroll
  for (int jj = 0; jj < 16; jj++) acc[jj] = b32[obase + jj];
#pragma unroll 1
  for (int k = 0; k < 3; k++) {
#pragma unroll 4
    for (int i = 0; i < 96; i++) {
      float xv = sIn[i * 67 + lane + k];
      const float* wp = W32t + ((size_t)(k * 96 + i)) * 96 + obase;  // wave-uniform -> s_loads
#pragma unroll
      for (int jj = 0; jj < 16; jj++) acc[jj] = fmaf(xv, wp[jj], acc[jj]);
    }
  }
  bool lok = lane < nouts;
#pragma unroll
  for (int jj = 0; jj < 16; jj++) {
    float v = lok ? fmaxf(acc[jj], 0.f) : 0.f;
#pragma unroll
    for (int m = 32; m >= 1; m >>= 1) v = fmaxf(v, __shfl_xor(v, m));
    if (lane == 0) atomicMax((unsigned int*)&F[b * 288 + 192 + obase + jj], __float_as_uint(v));
  }
}

// ---------------- final row-dot ----------------
__global__ __launch_bounds__(256) void outdot_kernel(const float* __restrict__ X,
    const float* __restrict__ W, const float* __restrict__ bptr, float* __restrict__ out)
{
  int r = blockIdx.x * 4 + (threadIdx.x >> 6);
  int lane = threadIdx.x & 63;
  float s = 0.f;
  for (int j = lane; j < 512; j += 64) s = fmaf(X[(size_t)r * 512 + j], W[j], s);
#pragma unroll
  for (int m = 32; m >= 1; m >>= 1) s += __shfl_xor(s, m);
  if (lane == 0) out[r] = s + bptr[0];
}

// ---------------- host-side dispatch ----------------
static inline void gemm2(hipStream_t st, int AMODE, int ACT,
                         const float* A, const float* B, const float* bias, float* C,
                         int M, int N, int K, const float* A2 = nullptr)
{
  dim3 g((N + 63) / 64, (M + 127) / 128), blk(256);
  if (AMODE == 0 && ACT == 0)      gemm2_k<0, 0><<<g, blk, 0, st>>>(A, B, bias, C, M, N, K, A2);
  else if (AMODE == 0 && ACT == 1) gemm2_k<0, 1><<<g, blk, 0, st>>>(A, B, bias, C, M, N, K, A2);
  else                             gemm2_k<1, 0><<<g, blk, 0, st>>>(A, B, bias, C, M, N, K, A2);
}

static inline void gemm3(hipStream_t st, int AMODE, int ACT,
                         const float* A, const float* B, const float* bias, float* C,
                         int M, int N, int K, const float* A2 = nullptr)
{
  dim3 g((N + 127) / 128, (M + 127) / 128), blk(256);
  if (AMODE == 0 && ACT == 0)      gemm3_k<0, 0><<<g, blk, 0, st>>>(A, B, bias, C, M, N, K, A2);
  else if (AMODE == 0 && ACT == 1) gemm3_k<0, 1><<<g, blk, 0, st>>>(A, B, bias, C, M, N, K, A2);
  else                             gemm3_k<1, 0><<<g, blk, 0, st>>>(A, B, bias, C, M, N, K, A2);
}

// split-K GEMM for small-M heads. N must be a power of two.
static inline void gemm_splitk(hipStream_t st, const float* A, const float* B,
                               const float* bias, float* C, int M, int N, int K,
                               int S, int act, float* PT)
{
  int KS = (K + S - 1) / S;
  dim3 g((N + 63) / 64, (M + 63) / 64, S);
  gemm_sk<<<g, 256, 0, st>>>(A, B, PT, M, N, K, KS);
  int MN = M * N;
  skred_kernel<<<(MN + 255) / 256, 256, 0, st>>>(PT, bias, C, MN, N - 1, S, act);
}

extern "C" void kernel_launch(void* const* d_in, const int* in_sizes, int n_in,
                              void* d_out, int out_size, void* d_ws, size_t ws_size,
                              hipStream_t stream)
{
  (void)in_sizes; (void)n_in; (void)out_size; (void)ws_size;
  const float* x      = (const float*)d_in[0];
  const float* adj    = (const float*)d_in[1];
  const int*   target = (const int*)  d_in[2];
  const float* z      = (const float*)d_in[3];
  const float* dec_W0 = (const float*)d_in[4];
  const float* dec_b0 = (const float*)d_in[5];
  const float* dec_g0 = (const float*)d_in[6];
  const float* dec_be0= (const float*)d_in[7];
  const float* dec_W1 = (const float*)d_in[8];
  const float* dec_b1 = (const float*)d_in[9];
  const float* dec_g1 = (const float*)d_in[10];
  const float* dec_be1= (const float*)d_in[11];
  const float* gW1    = (const float*)d_in[12];
  const float* gb1    = (const float*)d_in[13];
  const float* gW2    = (const float*)d_in[14];
  const float* gb2    = (const float*)d_in[15];
  const float* gW3    = (const float*)d_in[16];
  const float* gb3    = (const float*)d_in[17];
  const float* fcg1_W = (const float*)d_in[18];
  const float* fcg1_b = (const float*)d_in[19];
  const float* fcg2_W = (const float*)d_in[20];
  const float* fcg2_b = (const float*)d_in[21];
  const float* emb    = (const float*)d_in[22];
  const float* c10_W  = (const float*)d_in[23];
  const float* c10_b  = (const float*)d_in[24];
  const float* c20_W  = (const float*)d_in[25];
  const float* c20_b  = (const float*)d_in[26];
  const float* c21_W  = (const float*)d_in[27];
  const float* c21_b  = (const float*)d_in[28];
  const float* c30_W  = (const float*)d_in[29];
  const float* c30_b  = (const float*)d_in[30];
  const float* c31_W  = (const float*)d_in[31];
  const float* c31_b  = (const float*)d_in[32];
  const float* c32_W  = (const float*)d_in[33];
  const float* c32_b  = (const float*)d_in[34];
  const float* prot_W = (const float*)d_in[35];
  const float* prot_b = (const float*)d_in[36];
  const float* fc1_W  = (const float*)d_in[37];
  const float* fc1_b  = (const float*)d_in[38];
  const float* fc2_W  = (const float*)d_in[39];
  const float* fc2_b  = (const float*)d_in[40];
  const float* out_W  = (const float*)d_in[41];
  const float* out_b  = (const float*)d_in[42];
  float* out = (float*)d_out;
  float* ws = (float*)d_ws;

  float* H0   = ws + O_H0;   float* H1P  = ws + O_H1P;  float* X    = ws + O_X;
  float* A1   = ws + O_A1;   float* A2   = ws + O_A2;   float* A3   = ws + O_A3;
  float* XW1  = ws + O_XW1;  float* H1   = ws + O_H1;   float* H4   = ws + O_H4;
  float* H1W2 = ws + O_H1W2; float* H2   = ws + O_H2;
  float* H2W3 = ws + O_H2W3; float* H4W2 = ws + O_H4W2;
  float* HG   = ws + O_HG;   float* FCG1O= ws + O_FCG1O;
  float* Mt   = ws + O_M;    float* F    = ws + O_F;    float* V    = ws + O_V;
  float* XC   = ws + O_XC;   float* FC1O = ws + O_FC1O; float* FC2O = ws + O_FC2O;
  float* PS   = ws + O_PART; float* PQ   = ws + O_PART + 16384;
  float* MV   = ws + O_MV;   float* SK   = ws + O_SK;
  float* R10  = ws + O_R10;  float* R20  = ws + O_R20;  float* R30  = ws + O_R30;
  float* N21  = ws + O_N21;  float* N31  = ws + O_N31;
  float* BT21 = ws + O_BT21; float* BT31 = ws + O_BT31; float* W32T = ws + O_W32T;

  // ---- decoder (frozen cVAE) ----
  gemm2(stream, 1, 0, z, dec_W0, dec_b0, H0, 16384, 256, 142, x);
  bn_partial<<<dim3(4, 64), 256, 0, stream>>>(H0, PS, PQ, 256);
  bn_final<<<1, 256, 0, stream>>>(PS, PQ, MV, 256);
  bn_norm<<<16384, 256, 0, stream>>>(H0, H0, MV, dec_g0, dec_be0, 256, 256, 16384 * 256, 1, nullptr);
  gemm2(stream, 0, 0, H0, dec_W1, dec_b1, H1P, 16384, 78, 256);
  bn_partial<<<dim3(2, 64), 256, 0, stream>>>(H1P, PS, PQ, 78);
  bn_final<<<1, 256, 0, stream>>>(PS, PQ, MV, 78);
  bn_norm<<<4995, 256, 0, stream>>>(H1P, X, MV, dec_g1, dec_be1, 78, 156, 16384 * 78, 2, x);

  // ---- adjacency powers + gcn_norm ----
  adj_kernel<<<512, 1024, 0, stream>>>(adj, A1, A2, A3);

  // ---- GCN stack (h3/h5/h6 fused into gmp-max writes -> HG) ----
  gemm3(stream, 0, 0, X, gW1, nullptr, XW1, 16384, 156, 156);
  agg3_kernel<<<dim3(3, 512, 3), 64, 0, stream>>>(A1, A2, A3, XW1, gb1, H1, H4, HG, 156);
  gemm3(stream, 0, 0, H1, gW2, nullptr, H1W2, 16384, 312, 156);
  agg_kernel<<<dim3(5, 512), 64, 0, stream>>>(A1, H1W2, gb2, H2, 312);
  gemm3(stream, 0, 0, H2, gW3, nullptr, H2W3, 16384, 624, 312);
  aggmax_kernel<<<dim3(10, 512), 64, 0, stream>>>(A1, H2W3, gb3, HG, 624, 0);
  gemm3(stream, 0, 0, H4, gW2, nullptr, H4W2, 16384, 312, 156);
  aggmax_kernel<<<dim3(5, 512), 64, 0, stream>>>(A2, H4W2, gb2, HG, 312, 624);

  // ---- graph head (split-K, partials in dead H0 region) ----
  gemm_splitk(stream, HG, fcg1_W, fcg1_b, FCG1O, 512, 1024, 1092, 4, 1, SK);
  gemm_splitk(stream, FCG1O, fcg2_W, fcg2_b, V, 512, 128, 1024, 8, 0, SK);
  attn_kernel<<<512, 64, 0, stream>>>(V, XC, 256, 0);

  // ---- protein branch ----
  hipMemsetAsync(F, 0, 512 * 288 * sizeof(float), stream);
  mtable_kernel<<<264, 256, 0, stream>>>(emb, c10_W, c20_W, c30_W, Mt);
  rtable_kernel<<<dim3(6591, 3), 256, 0, stream>>>(Mt, c10_b, c20_b, c30_b, R10, R20, R30);
  wtrans3_kernel<<<dim3(108, 3), 256, 0, stream>>>(c21_W, c31_W, c32_W, BT21, BT31, W32T);
  gemm3(stream, 0, 0, R20, BT21, nullptr, N21, 17576, 288, 96);
  gemm3(stream, 0, 0, R30, BT31, nullptr, N31, 17576, 288, 96);
  conv3_fused<<<dim3(16, 512), 384, 0, stream>>>(target, R10, N21, c21_b, N31, c31_b, W32T, c32_b, F);
  gemm_splitk(stream, F, prot_W, prot_b, V, 512, 128, 288, 4, 0, SK);
  attn_kernel<<<512, 64, 0, stream>>>(V, XC, 256, 128);

  // ---- final MLP (split-K) ----
  gemm_splitk(stream, XC, fc1_W, fc1_b, FC1O, 512, 1024, 256, 2, 1, SK);
  gemm_splitk(stream, FC1O, fc2_W, fc2_b, FC2O, 512, 512, 1024, 4, 1, SK);
  outdot_kernel<<<128, 256, 0, stream>>>(FC2O, out_W, out_b, out);
}